// Round 1
// baseline (1192.862 us; speedup 1.0000x reference)
//
#include <hip/hip_runtime.h>
#include <stdint.h>

#define NN 4096
#define NCLS 5
#define NWORD 64
#define SCORE_TH 0.05f
#define NMS_TH 0.3f

// monotone f32 -> u32 map (order-preserving, handles sign)
__device__ __forceinline__ uint32_t fmap(float f) {
    uint32_t u = __float_as_uint(f);
    return (u & 0x80000000u) ? ~u : (u | 0x80000000u);
}
__device__ __forceinline__ float funmap(uint32_t m) {
    uint32_t u = (m & 0x80000000u) ? (m & 0x7fffffffu) : ~m;
    return __uint_as_float(u);
}

__device__ __forceinline__ uint64_t shfl64(uint64_t x, int src) {
    uint32_t lo = (uint32_t)x, hi = (uint32_t)(x >> 32);
    lo = __shfl(lo, src, 64);
    hi = __shfl(hi, src, 64);
    return ((uint64_t)hi << 32) | lo;
}

// K1: softmax + bbox transform + clip. Writes out cols 0..5 and ws scores.
__global__ void k_prep(const float* __restrict__ prop, const float* __restrict__ pred,
                       const float* __restrict__ cls, float* __restrict__ out,
                       float* __restrict__ scores) {
    int i = blockIdx.x * 256 + threadIdx.x;
    if (i >= NN) return;
    const float* pr = prop + i * 7;
    float l0 = pr[1], l1 = pr[2], l2 = pr[3];
    float h0 = pr[4], h1 = pr[5], h2 = pr[6];
    float s0 = h0 - l0 + 1.f, s1 = h1 - l1 + 1.f, s2 = h2 - l2 + 1.f;
    float c0 = l0 + 0.5f * s0, c1 = l1 + 0.5f * s1, c2 = l2 + 0.5f * s2;

    float sc[6];
    float mx = -3.4e38f;
#pragma unroll
    for (int c = 0; c < 6; ++c) { sc[c] = cls[i * 6 + c]; mx = fmaxf(mx, sc[c]); }
    float sum = 0.f;
#pragma unroll
    for (int c = 0; c < 6; ++c) { sc[c] = expf(sc[c] - mx); sum += sc[c]; }
    float inv = 1.f / sum;

#pragma unroll
    for (int c = 1; c < 6; ++c) {
        const float* d = pred + i * 36 + c * 6;
        float dc0 = d[0] / 10.f, dc1 = d[1] / 10.f, dc2 = d[2] / 10.f;
        float ds0 = d[3] / 5.f, ds1 = d[4] / 5.f, ds2 = d[5] / 5.f;
        float pc0 = dc0 * s0 + c0, pc1 = dc1 * s1 + c1, pc2 = dc2 * s2 + c2;
        float ps0 = expf(ds0) * s0, ps1 = expf(ds1) * s1, ps2 = expf(ds2) * s2;
        float o0 = fminf(fmaxf(pc0 - 0.5f * ps0, 0.f), 1023.f);
        float o1 = fminf(fmaxf(pc1 - 0.5f * ps1, 0.f), 1023.f);
        float o2 = fminf(fmaxf(pc2 - 0.5f * ps2, 0.f), 1023.f);
        float o3 = fminf(fmaxf(pc0 + 0.5f * ps0 - 1.f, 0.f), 1023.f);
        float o4 = fminf(fmaxf(pc1 + 0.5f * ps1 - 1.f, 0.f), 1023.f);
        float o5 = fminf(fmaxf(pc2 + 0.5f * ps2 - 1.f, 0.f), 1023.f);
        float* ob = out + ((size_t)(c - 1) * NN + i) * 7;
        ob[0] = o0; ob[1] = o1; ob[2] = o2; ob[3] = o3; ob[4] = o4; ob[5] = o5;
        scores[(c - 1) * NN + i] = sc[c] * inv;
    }
}

// K2: O(N^2) counting rank-sort, stable (score desc, idx asc) == argsort(-s) stable.
// Writes order[], sorted scores, gathered sorted boxes.
__global__ void k_sort(const float* __restrict__ scores, const float* __restrict__ out,
                       float* __restrict__ sscores, int* __restrict__ order,
                       float* __restrict__ sboxes) {
    int c = blockIdx.y;
    int i = blockIdx.x * 256 + threadIdx.x;
    const float* s = scores + c * NN;
    float si = s[i];
    uint32_t mi = fmap(si);
    __shared__ float tile[256];
    int rank = 0;
    for (int t = 0; t < NN / 256; ++t) {
        __syncthreads();
        tile[threadIdx.x] = s[t * 256 + threadIdx.x];
        __syncthreads();
#pragma unroll 8
        for (int jj = 0; jj < 256; ++jj) {
            uint32_t mj = fmap(tile[jj]);
            int j = t * 256 + jj;
            rank += (mj > mi) || (mj == mi && j < i);
        }
    }
    order[c * NN + rank] = i;
    sscores[c * NN + rank] = si;
    const float* b = out + ((size_t)c * NN + i) * 7;
    float* sb = sboxes + ((size_t)c * NN + rank) * 6;
#pragma unroll
    for (int k = 0; k < 6; ++k) sb[k] = b[k];
}

// K3: suppression bitmask. mask[c][r][cb] bit j2 = (j>r && iou>TH) for j=cb*64+j2.
// diag[c][r] = mask[c][r][r>>6] stored contiguously for the sequential pass.
__global__ void k_mask(const float* __restrict__ sboxes, uint64_t* __restrict__ mask,
                       uint64_t* __restrict__ diag) {
    int cb = blockIdx.x, rb = blockIdx.y, c = blockIdx.z;
    int t = threadIdx.x;  // 64 threads
    int r = rb * 64 + t;
    uint64_t bits = 0;
    if (cb >= rb) {
        __shared__ float rB[64][6], cB[64][6], cV[64];
#pragma unroll
        for (int k = 0; k < 6; ++k) rB[t][k] = sboxes[((size_t)c * NN + rb * 64 + t) * 6 + k];
#pragma unroll
        for (int k = 0; k < 6; ++k) cB[t][k] = sboxes[((size_t)c * NN + cb * 64 + t) * 6 + k];
        cV[t] = (cB[t][3] - cB[t][0] + 1.f) * (cB[t][4] - cB[t][1] + 1.f) * (cB[t][5] - cB[t][2] + 1.f);
        __syncthreads();
        float rl0 = rB[t][0], rl1 = rB[t][1], rl2 = rB[t][2];
        float rh0 = rB[t][3], rh1 = rB[t][4], rh2 = rB[t][5];
        float vi = (rh0 - rl0 + 1.f) * (rh1 - rl1 + 1.f) * (rh2 - rl2 + 1.f);
        for (int j2 = 0; j2 < 64; ++j2) {
            int j = cb * 64 + j2;
            if (j > r) {
                float w0 = fmaxf(fminf(rh0, cB[j2][3]) - fmaxf(rl0, cB[j2][0]) + 1.f, 0.f);
                float w1 = fmaxf(fminf(rh1, cB[j2][4]) - fmaxf(rl1, cB[j2][1]) + 1.f, 0.f);
                float w2 = fmaxf(fminf(rh2, cB[j2][5]) - fmaxf(rl2, cB[j2][2]) + 1.f, 0.f);
                float inter = w0 * w1 * w2;
                float iou = inter / (vi + cV[j2] - inter);
                if (iou > NMS_TH) bits |= 1ull << j2;
            }
        }
    }
    mask[((size_t)c * NN + r) * NWORD + cb] = bits;
    if (cb == rb) diag[(size_t)c * NN + r] = bits;
}

// K4: sequential greedy reduce, one wave per class. Lane l owns remv word l.
__global__ void __launch_bounds__(64) k_nms(const float* __restrict__ sscores,
                                            const int* __restrict__ order,
                                            const uint64_t* __restrict__ mask,
                                            const uint64_t* __restrict__ diag,
                                            float* __restrict__ kept) {
    int c = blockIdx.x;
    int lane = threadIdx.x;
    const uint64_t* M = mask + (size_t)c * NN * NWORD;
    const uint64_t* D = diag + (size_t)c * NN;
    const float* ss = sscores + c * NN;

    // init remv with !(score > TH), ballot per word
    uint64_t remv = 0;
    for (int k = 0; k < 64; ++k) {
        float s = ss[k * 64 + lane];
        uint64_t b = __ballot(!(s > SCORE_TH));
        if (k == lane) remv = b;
    }

    for (int w = 0; w < 64; ++w) {
        uint64_t rw = shfl64(remv, w);
        const uint64_t* Mb = M + (size_t)(w * 64) * NWORD;
        const uint64_t* Db = D + w * 64;
#pragma unroll 8
        for (int b = 0; b < 64; ++b) {
            uint64_t mrow = Mb[(size_t)b * NWORD + lane];
            uint64_t md = Db[b];
            if (!((rw >> b) & 1)) { remv |= mrow; rw |= md; }
        }
    }

    // epilogue: scatter kept scores back to original index order
    __shared__ uint64_t sh[64];
    sh[lane] = remv;
    __syncthreads();
    for (int t = 0; t < 64; ++t) {
        int p = t * 64 + lane;
        bool kp = !((sh[t] >> lane) & 1);
        float s = ss[p];
        int oi = order[c * NN + p];
        kept[c * NN + oi] = kp ? s : 0.f;
    }
}

// K5: exact 100th-largest of 20480 values via 32-step bitwise radix select.
__global__ void __launch_bounds__(1024) k_topk(const float* __restrict__ kept,
                                               float* __restrict__ thr) {
    int tid = threadIdx.x;
    uint32_t v[20];
#pragma unroll
    for (int k = 0; k < 20; ++k) v[k] = fmap(kept[k * 1024 + tid]);
    __shared__ int red[16];
    __shared__ int tot;
    uint32_t pre = 0;
    for (int bit = 31; bit >= 0; --bit) {
        uint32_t cand = pre | (1u << bit);
        int cnt = 0;
#pragma unroll
        for (int k = 0; k < 20; ++k) cnt += (v[k] >= cand);
#pragma unroll
        for (int off = 32; off; off >>= 1) cnt += __shfl_down(cnt, off, 64);
        if ((tid & 63) == 0) red[tid >> 6] = cnt;
        __syncthreads();
        if (tid == 0) {
            int s = 0;
            for (int q = 0; q < 16; ++q) s += red[q];
            tot = s;
        }
        __syncthreads();
        if (tot >= 100) pre = cand;
    }
    if (tid == 0) thr[0] = funmap(pre);
}

// K6: write final score column
__global__ void k_final(const float* __restrict__ kept, const float* __restrict__ thr,
                        float* __restrict__ out) {
    int idx = blockIdx.x * 256 + threadIdx.x;  // 0..20479
    if (idx >= NCLS * NN) return;
    int c = idx >> 12;
    int i = idx & (NN - 1);
    float t = *thr;
    float v = kept[idx];
    out[((size_t)c * NN + i) * 7 + 6] = (v >= t) ? v : 0.f;
}

extern "C" void kernel_launch(void* const* d_in, const int* in_sizes, int n_in,
                              void* d_out, int out_size, void* d_ws, size_t ws_size,
                              hipStream_t stream) {
    const float* prop = (const float*)d_in[0];   // (4096,7)
    const float* pred = (const float*)d_in[1];   // (4096,36)
    const float* cls = (const float*)d_in[2];    // (4096,6)
    float* out = (float*)d_out;                  // (5,4096,7)

    // workspace layout
    float* f = (float*)d_ws;
    float* scores = f;                      // 5*4096
    float* sscores = f + 20480;             // 5*4096
    float* kept = f + 40960;                // 5*4096
    float* thr = f + 61440;                 // 1
    float* sboxes = f + 61504;              // 5*4096*6 = 122880
    int* order = (int*)(f + 184384);        // 5*4096
    uint64_t* diag = (uint64_t*)((char*)d_ws + (832ull << 10));   // 5*4096*8 = 160KB
    uint64_t* mask = (uint64_t*)((char*)d_ws + (1ull << 20));     // 5*4096*64*8 = 10MB

    k_prep<<<dim3(16), dim3(256), 0, stream>>>(prop, pred, cls, out, scores);
    k_sort<<<dim3(16, NCLS), dim3(256), 0, stream>>>(scores, out, sscores, order, sboxes);
    k_mask<<<dim3(64, 64, NCLS), dim3(64), 0, stream>>>(sboxes, mask, diag);
    k_nms<<<dim3(NCLS), dim3(64), 0, stream>>>(sscores, order, mask, diag, kept);
    k_topk<<<dim3(1), dim3(1024), 0, stream>>>(kept, thr);
    k_final<<<dim3(80), dim3(256), 0, stream>>>(kept, thr, out);
}

// Round 2
// 507.972 us; speedup vs baseline: 2.3483x; 2.3483x over previous
//
#include <hip/hip_runtime.h>
#include <stdint.h>

#define NN 4096
#define NCLS 5
#define NWORD 64
#define SCORE_TH 0.05f
#define NMS_TH 0.3f

// monotone f32 -> u32 map (order-preserving, handles sign)
__device__ __forceinline__ uint32_t fmap(float f) {
    uint32_t u = __float_as_uint(f);
    return (u & 0x80000000u) ? ~u : (u | 0x80000000u);
}
__device__ __forceinline__ float funmap(uint32_t m) {
    uint32_t u = (m & 0x80000000u) ? (m & 0x7fffffffu) : ~m;
    return __uint_as_float(u);
}

__device__ __forceinline__ uint64_t shfl64(uint64_t x, int src) {
    uint32_t lo = (uint32_t)x, hi = (uint32_t)(x >> 32);
    lo = __shfl(lo, src, 64);
    hi = __shfl(hi, src, 64);
    return ((uint64_t)hi << 32) | lo;
}

// K1: softmax + bbox transform + clip. Writes out cols 0..5 and ws scores.
__global__ void k_prep(const float* __restrict__ prop, const float* __restrict__ pred,
                       const float* __restrict__ cls, float* __restrict__ out,
                       float* __restrict__ scores) {
    int i = blockIdx.x * 256 + threadIdx.x;
    if (i >= NN) return;
    const float* pr = prop + i * 7;
    float l0 = pr[1], l1 = pr[2], l2 = pr[3];
    float h0 = pr[4], h1 = pr[5], h2 = pr[6];
    float s0 = h0 - l0 + 1.f, s1 = h1 - l1 + 1.f, s2 = h2 - l2 + 1.f;
    float c0 = l0 + 0.5f * s0, c1 = l1 + 0.5f * s1, c2 = l2 + 0.5f * s2;

    float sc[6];
    float mx = -3.4e38f;
#pragma unroll
    for (int c = 0; c < 6; ++c) { sc[c] = cls[i * 6 + c]; mx = fmaxf(mx, sc[c]); }
    float sum = 0.f;
#pragma unroll
    for (int c = 0; c < 6; ++c) { sc[c] = expf(sc[c] - mx); sum += sc[c]; }
    float inv = 1.f / sum;

#pragma unroll
    for (int c = 1; c < 6; ++c) {
        const float* d = pred + i * 36 + c * 6;
        float dc0 = d[0] / 10.f, dc1 = d[1] / 10.f, dc2 = d[2] / 10.f;
        float ds0 = d[3] / 5.f, ds1 = d[4] / 5.f, ds2 = d[5] / 5.f;
        float pc0 = dc0 * s0 + c0, pc1 = dc1 * s1 + c1, pc2 = dc2 * s2 + c2;
        float ps0 = expf(ds0) * s0, ps1 = expf(ds1) * s1, ps2 = expf(ds2) * s2;
        float o0 = fminf(fmaxf(pc0 - 0.5f * ps0, 0.f), 1023.f);
        float o1 = fminf(fmaxf(pc1 - 0.5f * ps1, 0.f), 1023.f);
        float o2 = fminf(fmaxf(pc2 - 0.5f * ps2, 0.f), 1023.f);
        float o3 = fminf(fmaxf(pc0 + 0.5f * ps0 - 1.f, 0.f), 1023.f);
        float o4 = fminf(fmaxf(pc1 + 0.5f * ps1 - 1.f, 0.f), 1023.f);
        float o5 = fminf(fmaxf(pc2 + 0.5f * ps2 - 1.f, 0.f), 1023.f);
        float* ob = out + ((size_t)(c - 1) * NN + i) * 7;
        ob[0] = o0; ob[1] = o1; ob[2] = o2; ob[3] = o3; ob[4] = o4; ob[5] = o5;
        scores[(c - 1) * NN + i] = sc[c] * inv;
    }
}

// K2: O(N^2) counting rank-sort, stable (score desc, idx asc) == argsort(-s) stable.
__global__ void k_sort(const float* __restrict__ scores, const float* __restrict__ out,
                       float* __restrict__ sscores, int* __restrict__ order,
                       float* __restrict__ sboxes) {
    int c = blockIdx.y;
    int i = blockIdx.x * 256 + threadIdx.x;
    const float* s = scores + c * NN;
    float si = s[i];
    uint32_t mi = fmap(si);
    __shared__ float tile[256];
    int rank = 0;
    for (int t = 0; t < NN / 256; ++t) {
        __syncthreads();
        tile[threadIdx.x] = s[t * 256 + threadIdx.x];
        __syncthreads();
#pragma unroll 8
        for (int jj = 0; jj < 256; ++jj) {
            uint32_t mj = fmap(tile[jj]);
            int j = t * 256 + jj;
            rank += (mj > mi) || (mj == mi && j < i);
        }
    }
    order[c * NN + rank] = i;
    sscores[c * NN + rank] = si;
    const float* b = out + ((size_t)c * NN + i) * 7;
    float* sb = sboxes + ((size_t)c * NN + rank) * 6;
#pragma unroll
    for (int k = 0; k < 6; ++k) sb[k] = b[k];
}

// K3: suppression bitmask. mask[c][r][cb] bit j2 = (j>r && iou>TH) for j=cb*64+j2.
// diag[c][r] = mask[c][r][r>>6] stored contiguously for the sequential pass.
__global__ void k_mask(const float* __restrict__ sboxes, uint64_t* __restrict__ mask,
                       uint64_t* __restrict__ diag) {
    int cb = blockIdx.x, rb = blockIdx.y, c = blockIdx.z;
    int t = threadIdx.x;  // 64 threads
    int r = rb * 64 + t;
    uint64_t bits = 0;
    if (cb >= rb) {
        __shared__ float rB[64][6], cB[64][6], cV[64];
#pragma unroll
        for (int k = 0; k < 6; ++k) rB[t][k] = sboxes[((size_t)c * NN + rb * 64 + t) * 6 + k];
#pragma unroll
        for (int k = 0; k < 6; ++k) cB[t][k] = sboxes[((size_t)c * NN + cb * 64 + t) * 6 + k];
        cV[t] = (cB[t][3] - cB[t][0] + 1.f) * (cB[t][4] - cB[t][1] + 1.f) * (cB[t][5] - cB[t][2] + 1.f);
        __syncthreads();
        float rl0 = rB[t][0], rl1 = rB[t][1], rl2 = rB[t][2];
        float rh0 = rB[t][3], rh1 = rB[t][4], rh2 = rB[t][5];
        float vi = (rh0 - rl0 + 1.f) * (rh1 - rl1 + 1.f) * (rh2 - rl2 + 1.f);
        for (int j2 = 0; j2 < 64; ++j2) {
            int j = cb * 64 + j2;
            if (j > r) {
                float w0 = fmaxf(fminf(rh0, cB[j2][3]) - fmaxf(rl0, cB[j2][0]) + 1.f, 0.f);
                float w1 = fmaxf(fminf(rh1, cB[j2][4]) - fmaxf(rl1, cB[j2][1]) + 1.f, 0.f);
                float w2 = fmaxf(fminf(rh2, cB[j2][5]) - fmaxf(rl2, cB[j2][2]) + 1.f, 0.f);
                float inter = w0 * w1 * w2;
                float iou = inter / (vi + cV[j2] - inter);
                if (iou > NMS_TH) bits |= 1ull << j2;
            }
        }
    }
    mask[((size_t)c * NN + r) * NWORD + cb] = bits;
    if (cb == rb) diag[(size_t)c * NN + r] = bits;
}

// K4: sequential greedy reduce, one wave per class. Lane l owns remv word l.
// Register-tile version: bulk-load the 64x64-word tile per round, run the
// 64-step suppression chain on registers (uniform scalar chain + vector ORs).
__global__ void __launch_bounds__(64) k_nms(const float* __restrict__ sscores,
                                            const int* __restrict__ order,
                                            const uint64_t* __restrict__ mask,
                                            const uint64_t* __restrict__ diag,
                                            float* __restrict__ kept) {
    int c = blockIdx.x;
    int lane = threadIdx.x;
    const uint64_t* M = mask + (size_t)c * NN * NWORD;
    const uint64_t* D = diag + (size_t)c * NN;
    const float* ss = sscores + c * NN;

    // init remv with !(score > TH), ballot per word
    uint64_t remv = 0;
    for (int k = 0; k < 64; ++k) {
        float s = ss[k * 64 + lane];
        uint64_t bb = __ballot(!(s > SCORE_TH));
        if (k == lane) remv = bb;
    }

#pragma unroll 1
    for (int w = 0; w < 64; ++w) {
        const uint64_t* Mb = M + (size_t)(w << 6) * NWORD;
        const uint64_t* Db = D + (w << 6);

        // bulk tile load: lane owns word-column `lane`, rows b=0..63 (coalesced 512B/row)
        uint64_t m[64];
#pragma unroll
        for (int b = 0; b < 64; ++b) m[b] = Mb[((size_t)b << 6) + lane];

        // rw = current removed-state of this block's word; force to SGPR so the
        // 64-step chain compiles to SALU, not a VALU-latency chain.
        uint64_t rws = shfl64(remv, w);
        uint32_t rlo = __builtin_amdgcn_readfirstlane((uint32_t)rws);
        uint32_t rhi = __builtin_amdgcn_readfirstlane((uint32_t)(rws >> 32));
        uint64_t rw = ((uint64_t)rhi << 32) | rlo;

#pragma unroll
        for (int b = 0; b < 64; ++b) {
            uint64_t dg = Db[b];  // uniform address -> scalar load, prefetchable
            uint64_t keepm = ((rw >> b) & 1) ? 0ull : ~0ull;
            remv |= m[b] & keepm;
            rw |= dg & keepm;
        }
    }

    // epilogue: scatter kept scores back to original index order
    __shared__ uint64_t sh[64];
    sh[lane] = remv;
    __syncthreads();
    for (int t = 0; t < 64; ++t) {
        int p = t * 64 + lane;
        bool kp = !((sh[t] >> lane) & 1);
        float s = ss[p];
        int oi = order[c * NN + p];
        kept[c * NN + oi] = kp ? s : 0.f;
    }
}

// K5: exact 100th-largest of 20480 values via 32-step bitwise radix select.
__global__ void __launch_bounds__(1024) k_topk(const float* __restrict__ kept,
                                               float* __restrict__ thr) {
    int tid = threadIdx.x;
    uint32_t v[20];
#pragma unroll
    for (int k = 0; k < 20; ++k) v[k] = fmap(kept[k * 1024 + tid]);
    __shared__ int red[16];
    __shared__ int tot;
    uint32_t pre = 0;
    for (int bit = 31; bit >= 0; --bit) {
        uint32_t cand = pre | (1u << bit);
        int cnt = 0;
#pragma unroll
        for (int k = 0; k < 20; ++k) cnt += (v[k] >= cand);
#pragma unroll
        for (int off = 32; off; off >>= 1) cnt += __shfl_down(cnt, off, 64);
        if ((tid & 63) == 0) red[tid >> 6] = cnt;
        __syncthreads();
        if (tid == 0) {
            int s = 0;
            for (int q = 0; q < 16; ++q) s += red[q];
            tot = s;
        }
        __syncthreads();
        if (tot >= 100) pre = cand;
    }
    if (tid == 0) thr[0] = funmap(pre);
}

// K6: write final score column
__global__ void k_final(const float* __restrict__ kept, const float* __restrict__ thr,
                        float* __restrict__ out) {
    int idx = blockIdx.x * 256 + threadIdx.x;  // 0..20479
    if (idx >= NCLS * NN) return;
    int c = idx >> 12;
    int i = idx & (NN - 1);
    float t = *thr;
    float v = kept[idx];
    out[((size_t)c * NN + i) * 7 + 6] = (v >= t) ? v : 0.f;
}

extern "C" void kernel_launch(void* const* d_in, const int* in_sizes, int n_in,
                              void* d_out, int out_size, void* d_ws, size_t ws_size,
                              hipStream_t stream) {
    const float* prop = (const float*)d_in[0];   // (4096,7)
    const float* pred = (const float*)d_in[1];   // (4096,36)
    const float* cls = (const float*)d_in[2];    // (4096,6)
    float* out = (float*)d_out;                  // (5,4096,7)

    // workspace layout
    float* f = (float*)d_ws;
    float* scores = f;                      // 5*4096
    float* sscores = f + 20480;             // 5*4096
    float* kept = f + 40960;                // 5*4096
    float* thr = f + 61440;                 // 1
    float* sboxes = f + 61504;              // 5*4096*6 = 122880
    int* order = (int*)(f + 184384);        // 5*4096
    uint64_t* diag = (uint64_t*)((char*)d_ws + (832ull << 10));   // 5*4096*8 = 160KB
    uint64_t* mask = (uint64_t*)((char*)d_ws + (1ull << 20));     // 5*4096*64*8 = 10MB

    k_prep<<<dim3(16), dim3(256), 0, stream>>>(prop, pred, cls, out, scores);
    k_sort<<<dim3(16, NCLS), dim3(256), 0, stream>>>(scores, out, sscores, order, sboxes);
    k_mask<<<dim3(64, 64, NCLS), dim3(64), 0, stream>>>(sboxes, mask, diag);
    k_nms<<<dim3(NCLS), dim3(64), 0, stream>>>(sscores, order, mask, diag, kept);
    k_topk<<<dim3(1), dim3(1024), 0, stream>>>(kept, thr);
    k_final<<<dim3(80), dim3(256), 0, stream>>>(kept, thr, out);
}

// Round 3
// 470.196 us; speedup vs baseline: 2.5369x; 1.0803x over previous
//
#include <hip/hip_runtime.h>
#include <stdint.h>

#define NN 4096
#define NCLS 5
#define NWORD 64
#define SCORE_TH 0.05f
#define NMS_TH 0.3f

// monotone f32 -> u32 map (order-preserving, handles sign)
__device__ __forceinline__ uint32_t fmap(float f) {
    uint32_t u = __float_as_uint(f);
    return (u & 0x80000000u) ? ~u : (u | 0x80000000u);
}
__device__ __forceinline__ float funmap(uint32_t m) {
    uint32_t u = (m & 0x80000000u) ? (m & 0x7fffffffu) : ~m;
    return __uint_as_float(u);
}

__device__ __forceinline__ uint64_t shfl64(uint64_t x, int src) {
    uint32_t lo = (uint32_t)x, hi = (uint32_t)(x >> 32);
    lo = __shfl(lo, src, 64);
    hi = __shfl(hi, src, 64);
    return ((uint64_t)hi << 32) | lo;
}

// K1: softmax + bbox transform + clip. Writes out cols 0..5 and u64 sort keys.
__global__ void k_prep(const float* __restrict__ prop, const float* __restrict__ pred,
                       const float* __restrict__ cls, float* __restrict__ out,
                       uint64_t* __restrict__ skey) {
    int i = blockIdx.x * 256 + threadIdx.x;
    if (i >= NN) return;
    const float* pr = prop + i * 7;
    float l0 = pr[1], l1 = pr[2], l2 = pr[3];
    float h0 = pr[4], h1 = pr[5], h2 = pr[6];
    float s0 = h0 - l0 + 1.f, s1 = h1 - l1 + 1.f, s2 = h2 - l2 + 1.f;
    float c0 = l0 + 0.5f * s0, c1 = l1 + 0.5f * s1, c2 = l2 + 0.5f * s2;

    float sc[6];
    float mx = -3.4e38f;
#pragma unroll
    for (int c = 0; c < 6; ++c) { sc[c] = cls[i * 6 + c]; mx = fmaxf(mx, sc[c]); }
    float sum = 0.f;
#pragma unroll
    for (int c = 0; c < 6; ++c) { sc[c] = expf(sc[c] - mx); sum += sc[c]; }
    float inv = 1.f / sum;

#pragma unroll
    for (int c = 1; c < 6; ++c) {
        const float* d = pred + i * 36 + c * 6;
        float dc0 = d[0] / 10.f, dc1 = d[1] / 10.f, dc2 = d[2] / 10.f;
        float ds0 = d[3] / 5.f, ds1 = d[4] / 5.f, ds2 = d[5] / 5.f;
        float pc0 = dc0 * s0 + c0, pc1 = dc1 * s1 + c1, pc2 = dc2 * s2 + c2;
        float ps0 = expf(ds0) * s0, ps1 = expf(ds1) * s1, ps2 = expf(ds2) * s2;
        float o0 = fminf(fmaxf(pc0 - 0.5f * ps0, 0.f), 1023.f);
        float o1 = fminf(fmaxf(pc1 - 0.5f * ps1, 0.f), 1023.f);
        float o2 = fminf(fmaxf(pc2 - 0.5f * ps2, 0.f), 1023.f);
        float o3 = fminf(fmaxf(pc0 + 0.5f * ps0 - 1.f, 0.f), 1023.f);
        float o4 = fminf(fmaxf(pc1 + 0.5f * ps1 - 1.f, 0.f), 1023.f);
        float o5 = fminf(fmaxf(pc2 + 0.5f * ps2 - 1.f, 0.f), 1023.f);
        float* ob = out + ((size_t)(c - 1) * NN + i) * 7;
        ob[0] = o0; ob[1] = o1; ob[2] = o2; ob[3] = o3; ob[4] = o4; ob[5] = o5;
        float score = sc[c] * inv;
        // key: (mapped score desc, index asc) -> single u64 greater-than compare
        skey[(c - 1) * NN + i] = ((uint64_t)fmap(score) << 12) | (uint32_t)(4095 - i);
    }
}

// K2: O(N^2) counting rank-sort via u64 keys (2 VALU/elem, uniform key loads).
__global__ void __launch_bounds__(256) k_sort(const uint64_t* __restrict__ skey,
                                              const float* __restrict__ out,
                                              float* __restrict__ sscores,
                                              unsigned short* __restrict__ order,
                                              float* __restrict__ sboxes) {
    int c = blockIdx.y;
    int i = blockIdx.x * 256 + threadIdx.x;
    const uint64_t* K = skey + c * NN;
    uint64_t ki = K[i];
    int r0 = 0, r1 = 0, r2 = 0, r3 = 0;
#pragma unroll 4
    for (int j = 0; j < NN; j += 4) {
        r0 += (K[j] > ki);
        r1 += (K[j + 1] > ki);
        r2 += (K[j + 2] > ki);
        r3 += (K[j + 3] > ki);
    }
    int rank = (r0 + r1) + (r2 + r3);
    int io = c * NN + rank;
    order[io] = (unsigned short)i;
    sscores[io] = funmap((uint32_t)(ki >> 12));
    const float* b = out + ((size_t)c * NN + i) * 7;
    float* sb = sboxes + (size_t)io * 6;
#pragma unroll
    for (int k = 0; k < 6; ++k) sb[k] = b[k];
}

// K3: suppression bitmask, UPPER TRIANGLE ONLY (cb>=rb). 4 waves/block, each wave
// one (rb,cb) tile. diag[c][r] = within-block word, stored contiguously.
__global__ void __launch_bounds__(256) k_mask(const float* __restrict__ sboxes,
                                              uint64_t* __restrict__ mask,
                                              uint64_t* __restrict__ diag) {
    int tid = threadIdx.x;
    int wid = tid >> 6, lane = tid & 63;
    int rb = blockIdx.y, c = blockIdx.z;
    int cb = rb + blockIdx.x * 4 + wid;
    bool active = (cb < 64);

    __shared__ float cB[4][64][6];
    __shared__ float cV[4][64];

    int r = rb * 64 + lane;
    const float* rp = sboxes + ((size_t)c * NN + r) * 6;
    float rl0 = rp[0], rl1 = rp[1], rl2 = rp[2];
    float rh0 = rp[3], rh1 = rp[4], rh2 = rp[5];
    float vi = (rh0 - rl0 + 1.f) * (rh1 - rl1 + 1.f) * (rh2 - rl2 + 1.f);

    if (active) {
        const float* cp = sboxes + ((size_t)c * NN + cb * 64 + lane) * 6;
#pragma unroll
        for (int k = 0; k < 6; ++k) cB[wid][lane][k] = cp[k];
        cV[wid][lane] = (cB[wid][lane][3] - cB[wid][lane][0] + 1.f) *
                        (cB[wid][lane][4] - cB[wid][lane][1] + 1.f) *
                        (cB[wid][lane][5] - cB[wid][lane][2] + 1.f);
    }
    __syncthreads();
    if (!active) return;

    uint64_t bits = 0;
    for (int j2 = 0; j2 < 64; ++j2) {
        int j = cb * 64 + j2;
        if (j > r) {
            float w0 = fmaxf(fminf(rh0, cB[wid][j2][3]) - fmaxf(rl0, cB[wid][j2][0]) + 1.f, 0.f);
            float w1 = fmaxf(fminf(rh1, cB[wid][j2][4]) - fmaxf(rl1, cB[wid][j2][1]) + 1.f, 0.f);
            float w2 = fmaxf(fminf(rh2, cB[wid][j2][5]) - fmaxf(rl2, cB[wid][j2][2]) + 1.f, 0.f);
            float inter = w0 * w1 * w2;
            float iou = inter / (vi + cV[wid][j2] - inter);
            if (iou > NMS_TH) bits |= 1ull << j2;
        }
    }
    mask[((size_t)c * NN + r) * NWORD + cb] = bits;
    if (cb == rb) diag[(size_t)c * NN + r] = bits;
}

// K4: sequential greedy reduce, one wave per class.
// Double-buffered 64x64-word register tiles (256 VGPRs), scalar keep-chain on
// s_loaded diag words, exec-masked (lane>=w) vector ORs. Lower triangle never read.
__global__ void __launch_bounds__(64) k_nms(const float* __restrict__ sscores,
                                            const unsigned short* __restrict__ order,
                                            const uint64_t* __restrict__ mask,
                                            const uint64_t* __restrict__ diag,
                                            float* __restrict__ kept) {
    int c = blockIdx.x;
    int lane = threadIdx.x;
    const uint64_t* M = mask + (size_t)c * NN * NWORD;
    const uint64_t* D = diag + (size_t)c * NN;
    const float* ss = sscores + c * NN;

    // init remv: lane l owns word l = indices l*64..l*64+63; bit j = !(score>TH)
    uint64_t remv = 0;
    {
        const float4* sl = (const float4*)(ss + lane * 64);
#pragma unroll
        for (int q = 0; q < 16; ++q) {
            float4 v = sl[q];
            if (!(v.x > SCORE_TH)) remv |= 1ull << (q * 4);
            if (!(v.y > SCORE_TH)) remv |= 1ull << (q * 4 + 1);
            if (!(v.z > SCORE_TH)) remv |= 1ull << (q * 4 + 2);
            if (!(v.w > SCORE_TH)) remv |= 1ull << (q * 4 + 3);
        }
    }

    uint64_t bufA[64], bufB[64];

    // preload round 0 tile (rows 0..63, column word = lane)
#pragma unroll
    for (int b = 0; b < 64; ++b) bufA[b] = M[((size_t)b << 6) + lane];
    __builtin_amdgcn_sched_barrier(0);

    auto prefetch = [&](uint64_t* buf, int w) {
        if (w < 64) {
            const uint64_t* Mb = M + ((size_t)w << 12);
            if (lane >= w) {
#pragma unroll
                for (int b = 0; b < 64; ++b) buf[b] = Mb[((size_t)b << 6) + lane];
            }
        }
        __builtin_amdgcn_sched_barrier(0);
    };

    auto process = [&](const uint64_t* buf, int w) {
        uint64_t rws = shfl64(remv, w);
        uint32_t rlo = __builtin_amdgcn_readfirstlane((uint32_t)rws);
        uint32_t rhi = __builtin_amdgcn_readfirstlane((uint32_t)(rws >> 32));
        uint64_t rw = ((uint64_t)rhi << 32) | rlo;
        const uint64_t* Db = D + (w << 6);
        uint64_t kmask = 0;
#pragma unroll
        for (int b = 0; b < 64; ++b) {
            uint64_t dg = Db[b];   // uniform address -> scalar load
            bool keep = ((rw >> b) & 1) == 0;
            kmask |= keep ? (1ull << b) : 0ull;
            rw |= keep ? dg : 0ull;
        }
        if (lane >= w) {
#pragma unroll
            for (int b = 0; b < 64; ++b) {
                uint64_t km = ((kmask >> b) & 1) ? ~0ull : 0ull;
                remv |= buf[b] & km;
            }
        }
        __builtin_amdgcn_sched_barrier(0);
    };

#pragma unroll 1
    for (int w = 0; w < 64; w += 2) {
        prefetch(bufB, w + 1);
        process(bufA, w);
        prefetch(bufA, w + 2);
        process(bufB, w + 1);
    }

    // epilogue: scatter kept scores back to original index order
    __shared__ uint64_t sh[64];
    sh[lane] = remv;
    __syncthreads();
    const unsigned short* ord = order + c * NN;
    for (int t = 0; t < 64; ++t) {
        int p = t * 64 + lane;
        bool kp = !((sh[t] >> lane) & 1);
        float s = ss[p];
        int oi = ord[p];
        kept[c * NN + oi] = kp ? s : 0.f;
    }
}

// K5: exact 100th-largest of 20480 via 32-step bitwise radix select + final write.
__global__ void __launch_bounds__(1024) k_topk_final(const float* __restrict__ kept,
                                                     float* __restrict__ out) {
    int tid = threadIdx.x;
    uint32_t v[20];
#pragma unroll
    for (int k = 0; k < 20; ++k) v[k] = fmap(kept[k * 1024 + tid]);
    __shared__ int red[16];
    __shared__ int tot;
    uint32_t pre = 0;
    for (int bit = 31; bit >= 0; --bit) {
        uint32_t cand = pre | (1u << bit);
        int cnt = 0;
#pragma unroll
        for (int k = 0; k < 20; ++k) cnt += (v[k] >= cand);
#pragma unroll
        for (int off = 32; off; off >>= 1) cnt += __shfl_down(cnt, off, 64);
        if ((tid & 63) == 0) red[tid >> 6] = cnt;
        __syncthreads();
        if (tid == 0) {
            int s = 0;
            for (int q = 0; q < 16; ++q) s += red[q];
            tot = s;
        }
        __syncthreads();
        if (tot >= 100) pre = cand;
    }
    // final column write: keep iff mapped value >= pre (exact reference semantics)
#pragma unroll
    for (int k = 0; k < 20; ++k) {
        int idx = k * 1024 + tid;
        int c = idx >> 12;
        int i = idx & (NN - 1);
        out[((size_t)c * NN + i) * 7 + 6] = (v[k] >= pre) ? funmap(v[k]) : 0.f;
    }
}

extern "C" void kernel_launch(void* const* d_in, const int* in_sizes, int n_in,
                              void* d_out, int out_size, void* d_ws, size_t ws_size,
                              hipStream_t stream) {
    const float* prop = (const float*)d_in[0];   // (4096,7)
    const float* pred = (const float*)d_in[1];   // (4096,36)
    const float* cls = (const float*)d_in[2];    // (4096,6)
    float* out = (float*)d_out;                  // (5,4096,7)

    // workspace layout (total 11MB, same footprint as the passing run)
    char* base = (char*)d_ws;
    uint64_t* skey = (uint64_t*)base;                         // 160KB [0,160K)
    uint64_t* diag = (uint64_t*)(base + (160ull << 10));      // 160KB [160K,320K)
    float* sscores = (float*)(base + (320ull << 10));         // 80KB  [320K,400K)
    float* kept = (float*)(base + (400ull << 10));            // 80KB  [400K,480K)
    unsigned short* order = (unsigned short*)(base + (480ull << 10)); // 40KB [480K,520K)
    float* sboxes = (float*)(base + (528ull << 10));          // 480KB [528K,1008K)
    uint64_t* mask = (uint64_t*)(base + (1ull << 20));        // 10MB  [1M,11M)

    k_prep<<<dim3(16), dim3(256), 0, stream>>>(prop, pred, cls, out, skey);
    k_sort<<<dim3(16, NCLS), dim3(256), 0, stream>>>(skey, out, sscores, order, sboxes);
    k_mask<<<dim3(16, 64, NCLS), dim3(256), 0, stream>>>(sboxes, mask, diag);
    k_nms<<<dim3(NCLS), dim3(64), 0, stream>>>(sscores, order, mask, diag, kept);
    k_topk_final<<<dim3(1), dim3(1024), 0, stream>>>(kept, out);
}

// Round 4
// 469.836 us; speedup vs baseline: 2.5389x; 1.0008x over previous
//
#include <hip/hip_runtime.h>
#include <stdint.h>

#define NN 4096
#define NCLS 5
#define NWORD 64
#define SCORE_TH 0.05f
#define NMS_TH 0.3f

// monotone f32 -> u32 map (order-preserving, handles sign)
__device__ __forceinline__ uint32_t fmap(float f) {
    uint32_t u = __float_as_uint(f);
    return (u & 0x80000000u) ? ~u : (u | 0x80000000u);
}
__device__ __forceinline__ float funmap(uint32_t m) {
    uint32_t u = (m & 0x80000000u) ? (m & 0x7fffffffu) : ~m;
    return __uint_as_float(u);
}

__device__ __forceinline__ uint64_t shfl64(uint64_t x, int src) {
    uint32_t lo = (uint32_t)x, hi = (uint32_t)(x >> 32);
    lo = __shfl(lo, src, 64);
    hi = __shfl(hi, src, 64);
    return ((uint64_t)hi << 32) | lo;
}

// K1: softmax + bbox transform + clip. Writes out cols 0..5 and u64 sort keys.
__global__ void k_prep(const float* __restrict__ prop, const float* __restrict__ pred,
                       const float* __restrict__ cls, float* __restrict__ out,
                       uint64_t* __restrict__ skey) {
    int i = blockIdx.x * 256 + threadIdx.x;
    if (i >= NN) return;
    const float* pr = prop + i * 7;
    float l0 = pr[1], l1 = pr[2], l2 = pr[3];
    float h0 = pr[4], h1 = pr[5], h2 = pr[6];
    float s0 = h0 - l0 + 1.f, s1 = h1 - l1 + 1.f, s2 = h2 - l2 + 1.f;
    float c0 = l0 + 0.5f * s0, c1 = l1 + 0.5f * s1, c2 = l2 + 0.5f * s2;

    float sc[6];
    float mx = -3.4e38f;
#pragma unroll
    for (int c = 0; c < 6; ++c) { sc[c] = cls[i * 6 + c]; mx = fmaxf(mx, sc[c]); }
    float sum = 0.f;
#pragma unroll
    for (int c = 0; c < 6; ++c) { sc[c] = expf(sc[c] - mx); sum += sc[c]; }
    float inv = 1.f / sum;

#pragma unroll
    for (int c = 1; c < 6; ++c) {
        const float* d = pred + i * 36 + c * 6;
        float dc0 = d[0] / 10.f, dc1 = d[1] / 10.f, dc2 = d[2] / 10.f;
        float ds0 = d[3] / 5.f, ds1 = d[4] / 5.f, ds2 = d[5] / 5.f;
        float pc0 = dc0 * s0 + c0, pc1 = dc1 * s1 + c1, pc2 = dc2 * s2 + c2;
        float ps0 = expf(ds0) * s0, ps1 = expf(ds1) * s1, ps2 = expf(ds2) * s2;
        float o0 = fminf(fmaxf(pc0 - 0.5f * ps0, 0.f), 1023.f);
        float o1 = fminf(fmaxf(pc1 - 0.5f * ps1, 0.f), 1023.f);
        float o2 = fminf(fmaxf(pc2 - 0.5f * ps2, 0.f), 1023.f);
        float o3 = fminf(fmaxf(pc0 + 0.5f * ps0 - 1.f, 0.f), 1023.f);
        float o4 = fminf(fmaxf(pc1 + 0.5f * ps1 - 1.f, 0.f), 1023.f);
        float o5 = fminf(fmaxf(pc2 + 0.5f * ps2 - 1.f, 0.f), 1023.f);
        float* ob = out + ((size_t)(c - 1) * NN + i) * 7;
        ob[0] = o0; ob[1] = o1; ob[2] = o2; ob[3] = o3; ob[4] = o4; ob[5] = o5;
        float score = sc[c] * inv;
        // key: (mapped score desc, index asc) -> single u64 greater-than compare
        skey[(c - 1) * NN + i] = ((uint64_t)fmap(score) << 12) | (uint32_t)(4095 - i);
    }
}

// K2: O(N^2) counting rank-sort via u64 keys (2 VALU/elem, uniform key loads).
__global__ void __launch_bounds__(256) k_sort(const uint64_t* __restrict__ skey,
                                              const float* __restrict__ out,
                                              float* __restrict__ sscores,
                                              unsigned short* __restrict__ order,
                                              float* __restrict__ sboxes) {
    int c = blockIdx.y;
    int i = blockIdx.x * 256 + threadIdx.x;
    const uint64_t* K = skey + c * NN;
    uint64_t ki = K[i];
    int r0 = 0, r1 = 0, r2 = 0, r3 = 0;
#pragma unroll 4
    for (int j = 0; j < NN; j += 4) {
        r0 += (K[j] > ki);
        r1 += (K[j + 1] > ki);
        r2 += (K[j + 2] > ki);
        r3 += (K[j + 3] > ki);
    }
    int rank = (r0 + r1) + (r2 + r3);
    int io = c * NN + rank;
    order[io] = (unsigned short)i;
    sscores[io] = funmap((uint32_t)(ki >> 12));
    const float* b = out + ((size_t)c * NN + i) * 7;
    float* sb = sboxes + (size_t)io * 6;
#pragma unroll
    for (int k = 0; k < 6; ++k) sb[k] = b[k];
}

// K3: suppression bitmask, UPPER TRIANGLE ONLY (cb>=rb). 4 waves/block, each wave
// one (rb,cb) tile. diag[c][r] = within-block word, stored contiguously.
__global__ void __launch_bounds__(256) k_mask(const float* __restrict__ sboxes,
                                              uint64_t* __restrict__ mask,
                                              uint64_t* __restrict__ diag) {
    int tid = threadIdx.x;
    int wid = tid >> 6, lane = tid & 63;
    int rb = blockIdx.y, c = blockIdx.z;
    int cb = rb + blockIdx.x * 4 + wid;
    bool active = (cb < 64);

    __shared__ float cB[4][64][6];
    __shared__ float cV[4][64];

    int r = rb * 64 + lane;
    const float* rp = sboxes + ((size_t)c * NN + r) * 6;
    float rl0 = rp[0], rl1 = rp[1], rl2 = rp[2];
    float rh0 = rp[3], rh1 = rp[4], rh2 = rp[5];
    float vi = (rh0 - rl0 + 1.f) * (rh1 - rl1 + 1.f) * (rh2 - rl2 + 1.f);

    if (active) {
        const float* cp = sboxes + ((size_t)c * NN + cb * 64 + lane) * 6;
#pragma unroll
        for (int k = 0; k < 6; ++k) cB[wid][lane][k] = cp[k];
        cV[wid][lane] = (cB[wid][lane][3] - cB[wid][lane][0] + 1.f) *
                        (cB[wid][lane][4] - cB[wid][lane][1] + 1.f) *
                        (cB[wid][lane][5] - cB[wid][lane][2] + 1.f);
    }
    __syncthreads();
    if (!active) return;

    uint64_t bits = 0;
    for (int j2 = 0; j2 < 64; ++j2) {
        int j = cb * 64 + j2;
        if (j > r) {
            float w0 = fmaxf(fminf(rh0, cB[wid][j2][3]) - fmaxf(rl0, cB[wid][j2][0]) + 1.f, 0.f);
            float w1 = fmaxf(fminf(rh1, cB[wid][j2][4]) - fmaxf(rl1, cB[wid][j2][1]) + 1.f, 0.f);
            float w2 = fmaxf(fminf(rh2, cB[wid][j2][5]) - fmaxf(rl2, cB[wid][j2][2]) + 1.f, 0.f);
            float inter = w0 * w1 * w2;
            float iou = inter / (vi + cV[wid][j2] - inter);
            if (iou > NMS_TH) bits |= 1ull << j2;
        }
    }
    mask[((size_t)c * NN + r) * NWORD + cb] = bits;
    if (cb == rb) diag[(size_t)c * NN + r] = bits;
}

// K4: sequential greedy reduce, one wave per class.
// Double-buffered 64x64-word register tiles, scalar keep-chain on s_loaded diag
// words, exec-masked (lane>=w) vector ORs. Lower triangle never read.
// __launch_bounds__(64, 1): min 1 wave/EU -> 512-VGPR budget, so bufA/bufB
// (256 VGPRs) stay in registers. R3's 192-VGPR allocation spilled them to
// scratch, serializing every load at ~131 cy (measured 8365 cy/round).
__global__ void __launch_bounds__(64, 1) k_nms(const float* __restrict__ sscores,
                                               const unsigned short* __restrict__ order,
                                               const uint64_t* __restrict__ mask,
                                               const uint64_t* __restrict__ diag,
                                               float* __restrict__ kept) {
    int c = blockIdx.x;
    int lane = threadIdx.x;
    const uint64_t* M = mask + (size_t)c * NN * NWORD;
    const uint64_t* D = diag + (size_t)c * NN;
    const float* ss = sscores + c * NN;

    // init remv: lane l owns word l = indices l*64..l*64+63; bit j = !(score>TH)
    uint64_t remv = 0;
    {
        const float4* sl = (const float4*)(ss + lane * 64);
#pragma unroll
        for (int q = 0; q < 16; ++q) {
            float4 v = sl[q];
            if (!(v.x > SCORE_TH)) remv |= 1ull << (q * 4);
            if (!(v.y > SCORE_TH)) remv |= 1ull << (q * 4 + 1);
            if (!(v.z > SCORE_TH)) remv |= 1ull << (q * 4 + 2);
            if (!(v.w > SCORE_TH)) remv |= 1ull << (q * 4 + 3);
        }
    }

    uint64_t bufA[64], bufB[64];

    // preload round 0 tile (rows 0..63, column word = lane)
#pragma unroll
    for (int b = 0; b < 64; ++b) bufA[b] = M[((size_t)b << 6) + lane];
    __builtin_amdgcn_sched_barrier(0);

    auto prefetch = [&](uint64_t* buf, int w) {
        if (w < 64) {
            const uint64_t* Mb = M + ((size_t)w << 12);
            if (lane >= w) {
#pragma unroll
                for (int b = 0; b < 64; ++b) buf[b] = Mb[((size_t)b << 6) + lane];
            }
        }
        __builtin_amdgcn_sched_barrier(0);
    };

    auto process = [&](const uint64_t* buf, int w) {
        uint64_t rws = shfl64(remv, w);
        uint32_t rlo = __builtin_amdgcn_readfirstlane((uint32_t)rws);
        uint32_t rhi = __builtin_amdgcn_readfirstlane((uint32_t)(rws >> 32));
        uint64_t rw = ((uint64_t)rhi << 32) | rlo;
        const uint64_t* Db = D + (w << 6);
        uint64_t kmask = 0;
#pragma unroll
        for (int b = 0; b < 64; ++b) {
            uint64_t dg = Db[b];   // uniform address -> scalar load
            bool keep = ((rw >> b) & 1) == 0;
            kmask |= keep ? (1ull << b) : 0ull;
            rw |= keep ? dg : 0ull;
        }
        if (lane >= w) {
#pragma unroll
            for (int b = 0; b < 64; ++b) {
                uint64_t km = ((kmask >> b) & 1) ? ~0ull : 0ull;
                remv |= buf[b] & km;
            }
        }
        __builtin_amdgcn_sched_barrier(0);
    };

#pragma unroll 1
    for (int w = 0; w < 64; w += 2) {
        prefetch(bufB, w + 1);
        process(bufA, w);
        prefetch(bufA, w + 2);
        process(bufB, w + 1);
    }

    // epilogue: scatter kept scores back to original index order
    __shared__ uint64_t sh[64];
    sh[lane] = remv;
    __syncthreads();
    const unsigned short* ord = order + c * NN;
    for (int t = 0; t < 64; ++t) {
        int p = t * 64 + lane;
        bool kp = !((sh[t] >> lane) & 1);
        float s = ss[p];
        int oi = ord[p];
        kept[c * NN + oi] = kp ? s : 0.f;
    }
}

// K5: exact 100th-largest of 20480 via 32-step bitwise radix select + final write.
__global__ void __launch_bounds__(1024) k_topk_final(const float* __restrict__ kept,
                                                     float* __restrict__ out) {
    int tid = threadIdx.x;
    uint32_t v[20];
#pragma unroll
    for (int k = 0; k < 20; ++k) v[k] = fmap(kept[k * 1024 + tid]);
    __shared__ int red[16];
    __shared__ int tot;
    uint32_t pre = 0;
    for (int bit = 31; bit >= 0; --bit) {
        uint32_t cand = pre | (1u << bit);
        int cnt = 0;
#pragma unroll
        for (int k = 0; k < 20; ++k) cnt += (v[k] >= cand);
#pragma unroll
        for (int off = 32; off; off >>= 1) cnt += __shfl_down(cnt, off, 64);
        if ((tid & 63) == 0) red[tid >> 6] = cnt;
        __syncthreads();
        if (tid == 0) {
            int s = 0;
            for (int q = 0; q < 16; ++q) s += red[q];
            tot = s;
        }
        __syncthreads();
        if (tot >= 100) pre = cand;
    }
    // final column write: keep iff mapped value >= pre (exact reference semantics)
#pragma unroll
    for (int k = 0; k < 20; ++k) {
        int idx = k * 1024 + tid;
        int c = idx >> 12;
        int i = idx & (NN - 1);
        out[((size_t)c * NN + i) * 7 + 6] = (v[k] >= pre) ? funmap(v[k]) : 0.f;
    }
}

extern "C" void kernel_launch(void* const* d_in, const int* in_sizes, int n_in,
                              void* d_out, int out_size, void* d_ws, size_t ws_size,
                              hipStream_t stream) {
    const float* prop = (const float*)d_in[0];   // (4096,7)
    const float* pred = (const float*)d_in[1];   // (4096,36)
    const float* cls = (const float*)d_in[2];    // (4096,6)
    float* out = (float*)d_out;                  // (5,4096,7)

    // workspace layout (total 11MB)
    char* base = (char*)d_ws;
    uint64_t* skey = (uint64_t*)base;                         // 160KB [0,160K)
    uint64_t* diag = (uint64_t*)(base + (160ull << 10));      // 160KB [160K,320K)
    float* sscores = (float*)(base + (320ull << 10));         // 80KB  [320K,400K)
    float* kept = (float*)(base + (400ull << 10));            // 80KB  [400K,480K)
    unsigned short* order = (unsigned short*)(base + (480ull << 10)); // 40KB [480K,520K)
    float* sboxes = (float*)(base + (528ull << 10));          // 480KB [528K,1008K)
    uint64_t* mask = (uint64_t*)(base + (1ull << 20));        // 10MB  [1M,11M)

    k_prep<<<dim3(16), dim3(256), 0, stream>>>(prop, pred, cls, out, skey);
    k_sort<<<dim3(16, NCLS), dim3(256), 0, stream>>>(skey, out, sscores, order, sboxes);
    k_mask<<<dim3(16, 64, NCLS), dim3(256), 0, stream>>>(sboxes, mask, diag);
    k_nms<<<dim3(NCLS), dim3(64), 0, stream>>>(sscores, order, mask, diag, kept);
    k_topk_final<<<dim3(1), dim3(1024), 0, stream>>>(kept, out);
}

// Round 5
// 443.615 us; speedup vs baseline: 2.6890x; 1.0591x over previous
//
#include <hip/hip_runtime.h>
#include <stdint.h>

#define NN 4096
#define NCLS 5
#define NWORD 64
#define SCORE_TH 0.05f
#define NMS_TH 0.3f

// monotone f32 -> u32 map (order-preserving, handles sign)
__device__ __forceinline__ uint32_t fmap(float f) {
    uint32_t u = __float_as_uint(f);
    return (u & 0x80000000u) ? ~u : (u | 0x80000000u);
}
__device__ __forceinline__ float funmap(uint32_t m) {
    uint32_t u = (m & 0x80000000u) ? (m & 0x7fffffffu) : ~m;
    return __uint_as_float(u);
}

__device__ __forceinline__ uint64_t shfl64(uint64_t x, int src) {
    uint32_t lo = (uint32_t)x, hi = (uint32_t)(x >> 32);
    lo = __shfl(lo, src, 64);
    hi = __shfl(hi, src, 64);
    return ((uint64_t)hi << 32) | lo;
}

// async global->LDS, 16B/lane, lds dest = uniform base + lane*16 (HW-added)
__device__ __forceinline__ void gload_lds16(const void* g, void* l) {
    __builtin_amdgcn_global_load_lds(
        (const __attribute__((address_space(1))) uint32_t*)g,
        (__attribute__((address_space(3))) uint32_t*)l, 16, 0, 0);
}

// K1: softmax + bbox transform + clip. Writes out cols 0..5 and u64 sort keys.
__global__ void k_prep(const float* __restrict__ prop, const float* __restrict__ pred,
                       const float* __restrict__ cls, float* __restrict__ out,
                       uint64_t* __restrict__ skey) {
    int i = blockIdx.x * 256 + threadIdx.x;
    if (i >= NN) return;
    const float* pr = prop + i * 7;
    float l0 = pr[1], l1 = pr[2], l2 = pr[3];
    float h0 = pr[4], h1 = pr[5], h2 = pr[6];
    float s0 = h0 - l0 + 1.f, s1 = h1 - l1 + 1.f, s2 = h2 - l2 + 1.f;
    float c0 = l0 + 0.5f * s0, c1 = l1 + 0.5f * s1, c2 = l2 + 0.5f * s2;

    float sc[6];
    float mx = -3.4e38f;
#pragma unroll
    for (int c = 0; c < 6; ++c) { sc[c] = cls[i * 6 + c]; mx = fmaxf(mx, sc[c]); }
    float sum = 0.f;
#pragma unroll
    for (int c = 0; c < 6; ++c) { sc[c] = expf(sc[c] - mx); sum += sc[c]; }
    float inv = 1.f / sum;

#pragma unroll
    for (int c = 1; c < 6; ++c) {
        const float* d = pred + i * 36 + c * 6;
        float dc0 = d[0] / 10.f, dc1 = d[1] / 10.f, dc2 = d[2] / 10.f;
        float ds0 = d[3] / 5.f, ds1 = d[4] / 5.f, ds2 = d[5] / 5.f;
        float pc0 = dc0 * s0 + c0, pc1 = dc1 * s1 + c1, pc2 = dc2 * s2 + c2;
        float ps0 = expf(ds0) * s0, ps1 = expf(ds1) * s1, ps2 = expf(ds2) * s2;
        float o0 = fminf(fmaxf(pc0 - 0.5f * ps0, 0.f), 1023.f);
        float o1 = fminf(fmaxf(pc1 - 0.5f * ps1, 0.f), 1023.f);
        float o2 = fminf(fmaxf(pc2 - 0.5f * ps2, 0.f), 1023.f);
        float o3 = fminf(fmaxf(pc0 + 0.5f * ps0 - 1.f, 0.f), 1023.f);
        float o4 = fminf(fmaxf(pc1 + 0.5f * ps1 - 1.f, 0.f), 1023.f);
        float o5 = fminf(fmaxf(pc2 + 0.5f * ps2 - 1.f, 0.f), 1023.f);
        float* ob = out + ((size_t)(c - 1) * NN + i) * 7;
        ob[0] = o0; ob[1] = o1; ob[2] = o2; ob[3] = o3; ob[4] = o4; ob[5] = o5;
        float score = sc[c] * inv;
        // key: (mapped score desc, index asc) -> single u64 greater-than compare
        skey[(c - 1) * NN + i] = ((uint64_t)fmap(score) << 12) | (uint32_t)(4095 - i);
    }
}

// K2: O(N^2) counting rank-sort via u64 keys; 8 independent uniform loads per
// group so SMEM latency is pipelined even at ~1 wave/CU occupancy.
__global__ void __launch_bounds__(256) k_sort(const uint64_t* __restrict__ skey,
                                              const float* __restrict__ out,
                                              float* __restrict__ sscores,
                                              unsigned short* __restrict__ order,
                                              float* __restrict__ sboxes) {
    int c = blockIdx.y;
    int i = blockIdx.x * 256 + threadIdx.x;
    const uint64_t* K = skey + c * NN;
    uint64_t ki = K[i];
    int rank = 0;
#pragma unroll 2
    for (int j = 0; j < NN; j += 8) {
        uint64_t k0 = K[j], k1 = K[j + 1], k2 = K[j + 2], k3 = K[j + 3];
        uint64_t k4 = K[j + 4], k5 = K[j + 5], k6 = K[j + 6], k7 = K[j + 7];
        int a = (k0 > ki) + (k1 > ki) + (k2 > ki) + (k3 > ki);
        int b = (k4 > ki) + (k5 > ki) + (k6 > ki) + (k7 > ki);
        rank += a + b;
    }
    int io = c * NN + rank;
    order[io] = (unsigned short)i;
    sscores[io] = funmap((uint32_t)(ki >> 12));
    const float* b = out + ((size_t)c * NN + i) * 7;
    float* sb = sboxes + (size_t)io * 6;
#pragma unroll
    for (int k = 0; k < 6; ++k) sb[k] = b[k];
}

// K3: suppression bitmask, UPPER TRIANGLE ONLY (cb>=rb). 4 waves/block.
// diag[c][r] = within-block word, stored contiguously.
__global__ void __launch_bounds__(256) k_mask(const float* __restrict__ sboxes,
                                              uint64_t* __restrict__ mask,
                                              uint64_t* __restrict__ diag) {
    int tid = threadIdx.x;
    int wid = tid >> 6, lane = tid & 63;
    int rb = blockIdx.y, c = blockIdx.z;
    int cb = rb + blockIdx.x * 4 + wid;
    bool active = (cb < 64);

    __shared__ float cB[4][64][6];
    __shared__ float cV[4][64];

    int r = rb * 64 + lane;
    float rl0 = 0, rl1 = 0, rl2 = 0, rh0 = 0, rh1 = 0, rh2 = 0, vi = 0;
    if (active) {
        const float* rp = sboxes + ((size_t)c * NN + r) * 6;
        rl0 = rp[0]; rl1 = rp[1]; rl2 = rp[2];
        rh0 = rp[3]; rh1 = rp[4]; rh2 = rp[5];
        vi = (rh0 - rl0 + 1.f) * (rh1 - rl1 + 1.f) * (rh2 - rl2 + 1.f);
        const float* cp = sboxes + ((size_t)c * NN + cb * 64 + lane) * 6;
#pragma unroll
        for (int k = 0; k < 6; ++k) cB[wid][lane][k] = cp[k];
        cV[wid][lane] = (cB[wid][lane][3] - cB[wid][lane][0] + 1.f) *
                        (cB[wid][lane][4] - cB[wid][lane][1] + 1.f) *
                        (cB[wid][lane][5] - cB[wid][lane][2] + 1.f);
    }
    __syncthreads();
    if (!active) return;

    uint64_t bits = 0;
    for (int j2 = 0; j2 < 64; ++j2) {
        int j = cb * 64 + j2;
        if (j > r) {
            float w0 = fmaxf(fminf(rh0, cB[wid][j2][3]) - fmaxf(rl0, cB[wid][j2][0]) + 1.f, 0.f);
            float w1 = fmaxf(fminf(rh1, cB[wid][j2][4]) - fmaxf(rl1, cB[wid][j2][1]) + 1.f, 0.f);
            float w2 = fmaxf(fminf(rh2, cB[wid][j2][5]) - fmaxf(rl2, cB[wid][j2][2]) + 1.f, 0.f);
            float inter = w0 * w1 * w2;
            float iou = inter / (vi + cV[wid][j2] - inter);
            if (iou > NMS_TH) bits |= 1ull << j2;
        }
    }
    mask[((size_t)c * NN + r) * NWORD + cb] = bits;
    if (cb == rb) diag[(size_t)c * NN + r] = bits;
}

// K4: sequential greedy reduce, one wave per class.
// Tile lives in LDS (async global_load_lds double-buffer: zero VGPR cost —
// R3/R4's register tiles exceeded the 256-VGPR file and spilled to scratch,
// serializing at ~131 cy/load). Diag also staged to LDS in the prologue.
__global__ void __launch_bounds__(64, 1) k_nms(const float* __restrict__ sscores,
                                               const unsigned short* __restrict__ order,
                                               const uint64_t* __restrict__ mask,
                                               const uint64_t* __restrict__ diag,
                                               float* __restrict__ kept) {
    __shared__ __align__(16) uint64_t ltile[2][64 * 64];  // 2 x 32KB
    __shared__ __align__(16) uint64_t ldiag[NN];          // 32KB
    __shared__ uint64_t sh[64];

    int c = blockIdx.x;
    int lane = threadIdx.x;
    const uint64_t* M = mask + (size_t)c * NN * NWORD;
    const uint64_t* D = diag + (size_t)c * NN;
    const float* ss = sscores + c * NN;

    // prologue: stage diag (32KB) + tile0 (32KB) into LDS
    {
        const char* g = (const char*)D + lane * 16;
        char* l = (char*)ldiag;
#pragma unroll
        for (int i = 0; i < 32; ++i) gload_lds16(g + i * 1024, l + i * 1024);
    }
    {
        const char* g = (const char*)M + lane * 16;
        char* l = (char*)ltile[0];
#pragma unroll
        for (int i = 0; i < 32; ++i) gload_lds16(g + i * 1024, l + i * 1024);
    }

    // init remv: lane l owns word l = indices l*64..l*64+63; bit j = !(score>TH)
    uint64_t remv = 0;
    {
        const float4* sl = (const float4*)(ss + lane * 64);
#pragma unroll
        for (int q = 0; q < 16; ++q) {
            float4 v = sl[q];
            if (!(v.x > SCORE_TH)) remv |= 1ull << (q * 4);
            if (!(v.y > SCORE_TH)) remv |= 1ull << (q * 4 + 1);
            if (!(v.z > SCORE_TH)) remv |= 1ull << (q * 4 + 2);
            if (!(v.w > SCORE_TH)) remv |= 1ull << (q * 4 + 3);
        }
    }

    asm volatile("s_waitcnt vmcnt(0)" ::: "memory");
    __builtin_amdgcn_sched_barrier(0);

    int cur = 0;
#pragma unroll 1
    for (int w = 0; w < 64; ++w) {
        // prefetch next tile into the other LDS buffer (stays in flight
        // across the whole process phase; vmcnt(0) only at iteration end)
        if (w < 63) {
            const char* g = (const char*)(M + ((size_t)(w + 1) << 12)) + lane * 16;
            char* l = (char*)ltile[cur ^ 1];
#pragma unroll
            for (int i = 0; i < 32; ++i) gload_lds16(g + i * 1024, l + i * 1024);
        }
        __builtin_amdgcn_sched_barrier(0);

        // process current tile from LDS
        uint64_t rws = shfl64(remv, w);
        uint32_t rlo = __builtin_amdgcn_readfirstlane((uint32_t)rws);
        uint32_t rhi = __builtin_amdgcn_readfirstlane((uint32_t)(rws >> 32));
        uint64_t rw = ((uint64_t)rhi << 32) | rlo;
        const uint64_t* Dw = ldiag + (w << 6);
        const uint64_t* T = ltile[cur];
        uint64_t acc = 0;
#pragma unroll
        for (int b = 0; b < 64; ++b) {
            uint64_t dg = Dw[b];            // LDS broadcast read
            uint64_t mrow = T[(b << 6) | lane];  // LDS per-lane read
            uint64_t km = ((rw >> b) & 1) ? 0ull : ~0ull;
            rw |= dg & km;
            acc |= mrow & km;
        }
        // lower-triangle words are garbage (k_mask writes cb>=rb only): mask out
        if (lane >= w) remv |= acc;

        asm volatile("s_waitcnt vmcnt(0)" ::: "memory");
        __builtin_amdgcn_sched_barrier(0);
        cur ^= 1;
    }

    // epilogue: scatter kept scores back to original index order
    sh[lane] = remv;
    __syncthreads();
    const unsigned short* ord = order + c * NN;
    for (int t = 0; t < 64; ++t) {
        int p = t * 64 + lane;
        bool kp = !((sh[t] >> lane) & 1);
        float s = ss[p];
        int oi = ord[p];
        kept[c * NN + oi] = kp ? s : 0.f;
    }
}

// K5: exact 100th-largest of 20480 via 32-step bitwise radix select + final write.
__global__ void __launch_bounds__(1024) k_topk_final(const float* __restrict__ kept,
                                                     float* __restrict__ out) {
    int tid = threadIdx.x;
    uint32_t v[20];
#pragma unroll
    for (int k = 0; k < 20; ++k) v[k] = fmap(kept[k * 1024 + tid]);
    __shared__ int red[16];
    __shared__ int tot;
    uint32_t pre = 0;
    for (int bit = 31; bit >= 0; --bit) {
        uint32_t cand = pre | (1u << bit);
        int cnt = 0;
#pragma unroll
        for (int k = 0; k < 20; ++k) cnt += (v[k] >= cand);
#pragma unroll
        for (int off = 32; off; off >>= 1) cnt += __shfl_down(cnt, off, 64);
        if ((tid & 63) == 0) red[tid >> 6] = cnt;
        __syncthreads();
        if (tid == 0) {
            int s = 0;
            for (int q = 0; q < 16; ++q) s += red[q];
            tot = s;
        }
        __syncthreads();
        if (tot >= 100) pre = cand;
    }
    // final column write: keep iff mapped value >= pre (exact reference semantics)
#pragma unroll
    for (int k = 0; k < 20; ++k) {
        int idx = k * 1024 + tid;
        int c = idx >> 12;
        int i = idx & (NN - 1);
        out[((size_t)c * NN + i) * 7 + 6] = (v[k] >= pre) ? funmap(v[k]) : 0.f;
    }
}

extern "C" void kernel_launch(void* const* d_in, const int* in_sizes, int n_in,
                              void* d_out, int out_size, void* d_ws, size_t ws_size,
                              hipStream_t stream) {
    const float* prop = (const float*)d_in[0];   // (4096,7)
    const float* pred = (const float*)d_in[1];   // (4096,36)
    const float* cls = (const float*)d_in[2];    // (4096,6)
    float* out = (float*)d_out;                  // (5,4096,7)

    // workspace layout (total 11MB)
    char* base = (char*)d_ws;
    uint64_t* skey = (uint64_t*)base;                         // 160KB [0,160K)
    uint64_t* diag = (uint64_t*)(base + (160ull << 10));      // 160KB [160K,320K)
    float* sscores = (float*)(base + (320ull << 10));         // 80KB  [320K,400K)
    float* kept = (float*)(base + (400ull << 10));            // 80KB  [400K,480K)
    unsigned short* order = (unsigned short*)(base + (480ull << 10)); // 40KB [480K,520K)
    float* sboxes = (float*)(base + (528ull << 10));          // 480KB [528K,1008K)
    uint64_t* mask = (uint64_t*)(base + (1ull << 20));        // 10MB  [1M,11M)

    k_prep<<<dim3(16), dim3(256), 0, stream>>>(prop, pred, cls, out, skey);
    k_sort<<<dim3(16, NCLS), dim3(256), 0, stream>>>(skey, out, sscores, order, sboxes);
    k_mask<<<dim3(16, 64, NCLS), dim3(256), 0, stream>>>(sboxes, mask, diag);
    k_nms<<<dim3(NCLS), dim3(64), 0, stream>>>(sscores, order, mask, diag, kept);
    k_topk_final<<<dim3(1), dim3(1024), 0, stream>>>(kept, out);
}